// Round 5
// baseline (133.059 us; speedup 1.0000x reference)
//
#include <hip/hip_runtime.h>

// SingleStageDetector, R14 = clean-FIFO pipelined staging.
// Post-mortem of R9/R11/R13 (all ~42.5us): (a) LLVM scheduler SANK the
// staging loads to their LDS-write consumers (R13 VGPR=52 proves no
// register-held prefetch survived); (b) per-step A-frag prefetches were
// issued AFTER each chunk's staging loads, so every A-frag vmcnt wait
// force-drained the staging HBM loads (FIFO vmcnt) two MFMA steps into
// each chunk -> staging delivery serialized, HBM 26%.
// Fix:
//   - per-chunk A-burst: Ar[8] loaded at top of iter c, BEFORE
//     STAGE_ISSUE(c+1); waiting on Ar (oldest) drains nothing, staging
//     loads stay in flight across the whole compute phase.
//   - sched_barrier(0) pins [A-burst | ISSUE | compute | WRITE] order so
//     the scheduler cannot sink the staging loads again.
//   - STAGE_WRITE(c+1) therefore waits on loads issued one full
//     compute-phase (~3000 cyc, ds_read-bound) earlier ~ delivery time.
//   - IoU at the end (no foreign vmem waits inside the staging FIFO).
// Everything else proven in R8-R13: prep_w frag images, XOR-swizzled LDS,
// barrier placement, h-phase, GEMM2, epilogue.

#define CIN_  1280
#define HW_   49
#define HID_  128
#define OUTD_ 65
#define NGT_  40
#define NP_   441

// flat output offsets (elements), reference return order
#define CONF_OFF 0
#define OFFS_OFF 112896   // 256*9*49
#define CLS_OFF  564480   // + 256*9*4*49
#define IOU_OFF  815360   // + 256*20*49 ; total 5,331,200

// ws layout (u32): W1f frags ((K32*8+mt)*64+lane)*4+sub, then W2f frags
#define WS_W1F_U32 81920u
#define WS_W2F_U32 5120u

typedef __bf16 bf16x8 __attribute__((ext_vector_type(8)));
typedef float  f32x4  __attribute__((ext_vector_type(4)));

__device__ __forceinline__ unsigned pack2bf(float lo, float hi) {
    unsigned short a = __builtin_bit_cast(unsigned short, (__bf16)lo);
    unsigned short b = __builtin_bit_cast(unsigned short, (__bf16)hi);
    return (unsigned)a | ((unsigned)b << 16);   // compiler: v_cvt_pk_bf16_f32
}
__device__ __forceinline__ float sigmoidf_(float v) { return 1.f / (1.f + __expf(-v)); }

__device__ __forceinline__ bf16x8 ld_frag(const unsigned* p) {
    union { uint4 u; bf16x8 v; } x;
    x.u = *(const uint4*)p;                       // 16B-aligned ds_read_b128
    return x.v;
}
__device__ __forceinline__ bf16x8 as_bf(uint4 u) {
    union { uint4 u; bf16x8 v; } x; x.u = u; return x.v;
}

// ---------------------------------------------------------------------------
// prep_w: W1 (128,1280) + W2 (65,128) -> fragment-ready bf16 images. (R8.)
// ---------------------------------------------------------------------------
__global__ __launch_bounds__(256) void prep_w(
    const float* __restrict__ W1, const float* __restrict__ W2,
    unsigned* __restrict__ ws)
{
    int X = blockIdx.x * 256 + threadIdx.x;       // 0..87039
    if (X < (int)WS_W1F_U32) {
        int sub = X & 3, lane = (X >> 2) & 63, f = X >> 8;
        int mt = f & 7, K32 = f >> 3;
        int o = mt * 16 + (lane & 15);
        int c = K32 * 32 + (lane >> 4) * 8 + sub * 2;
        float2 v = *(const float2*)(W1 + o * CIN_ + c);
        ws[X] = pack2bf(v.x, v.y);
    } else {
        int Y = X - (int)WS_W1F_U32;              // 0..5119
        int sub = Y & 3, lane = (Y >> 2) & 63, f = Y >> 8;
        int mt2 = f % 5, ks2 = f / 5;
        int o2 = mt2 * 16 + (lane & 15);
        int c = ks2 * 32 + (lane >> 4) * 8 + sub * 2;
        unsigned val = 0;
        if (o2 < OUTD_) {
            float2 v = *(const float2*)(W2 + o2 * HID_ + c);
            val = pack2bf(v.x, v.y);
        }
        ws[WS_W1F_U32 + Y] = val;
    }
}

// ---------------------------------------------------------------------------
// fused_main: block = (b, half). LDS: 2 chunk buffers of 32 rows x 128 u32
// (256 channels as bf16 pairs), XOR swizzle on 16B slots
// (phys_slot = slot ^ (row&7)). smHT (32x68 u32) aliases buffer 0.
// ---------------------------------------------------------------------------
__global__ __launch_bounds__(512, 4) void fused_main(
    const float* __restrict__ F,     // (256,1280,7,7)
    const float* __restrict__ grd,   // (256,7,7,2)
    const float* __restrict__ bbox,  // (256,40,5)
    const float* __restrict__ anc,   // (9,2)
    const unsigned* __restrict__ wsW,
    const float* __restrict__ B1,    // (128,)
    const float* __restrict__ B2,    // (65,)
    float* __restrict__ out)
{
    __shared__ __align__(16) unsigned lds[2 * 32 * 128];   // 32,768 B
    unsigned* smHT = lds;                                  // aliased after K-loop

    const int tid  = threadIdx.x;
    const int b    = blockIdx.x >> 1;
    const int half = blockIdx.x & 1;
    const int lane = tid & 63;
    const int w    = tid >> 6;         // 0..7 = GEMM1 m-tile
    const int quad = lane >> 4;
    const int m16  = lane & 15;
    const int hw0  = half * 32;

    const float* Fb = F + b * (CIN_ * HW_);

    // staging decomposition (per chunk of 256 channels = 32 slots x 32 rows):
    // thread -> row = tid&31 (hw = hw0+row), slots cb0=2*(tid>>5), cb0+1.
    // Slot = 8 consecutive channels -> 8 loads -> 4 pack2bf -> ds_write_b128
    // at row*128 + ((cb ^ (row&7))<<2).  Even bank spread, conflict-free.
    const int srow = tid & 31;
    const int shw  = hw0 + srow;
    const bool sok = shw < HW_;
    const int cb0  = (tid >> 5) * 2;
    const float* Fs = Fb + shw;        // + ch*49

    float fl[16];                      // single staging register buffer
    #define STAGE_ISSUE(c)                                                   \
        if (sok) {                                                           \
            _Pragma("unroll")                                                \
            for (int u = 0; u < 2; ++u) {                                    \
                _Pragma("unroll")                                            \
                for (int j = 0; j < 8; ++j) {                                \
                    int ch = (c) * 256 + (cb0 + u) * 8 + j;                  \
                    fl[u * 8 + j] = Fs[ch * HW_];                            \
                }                                                            \
            }                                                                \
        }
    #define STAGE_WRITE(c)                                                   \
        if (sok) {                                                           \
            unsigned* dstb = lds + (((c) & 1) << 12) + srow * 128;           \
            _Pragma("unroll")                                                \
            for (int u = 0; u < 2; ++u) {                                    \
                int cb = cb0 + u;                                            \
                uint4 q;                                                     \
                q.x = pack2bf(fl[u * 8 + 0], fl[u * 8 + 1]);                 \
                q.y = pack2bf(fl[u * 8 + 2], fl[u * 8 + 3]);                 \
                q.z = pack2bf(fl[u * 8 + 4], fl[u * 8 + 5]);                 \
                q.w = pack2bf(fl[u * 8 + 6], fl[u * 8 + 7]);                 \
                *(uint4*)(dstb + ((cb ^ (srow & 7)) << 2)) = q;              \
            }                                                                \
        }

    // ---- prologue: zero pad rows (both buffers), stage chunk 0 ----
    if (!sok) {                        // only half=1 blocks have pad rows
        uint4 z = {0u, 0u, 0u, 0u};
        #pragma unroll
        for (int bf = 0; bf < 2; ++bf) {
            unsigned* dstb = lds + (bf << 12) + srow * 128;
            *(uint4*)(dstb + (((cb0    ) ^ (srow & 7)) << 2)) = z;
            *(uint4*)(dstb + (((cb0 + 1) ^ (srow & 7)) << 2)) = z;
        }
    }
    STAGE_ISSUE(0);
    STAGE_WRITE(0);                    // startup delivery stall (unavoidable)
    __syncthreads();

    // ---- chunked K-loop: 5 chunks x 8 K32-steps ----
    // Per iter c (FIFO-clean):
    //   Ar burst (8 loads)  | sched_barrier
    //   ISSUE(c+1) (16 ld)  | sched_barrier
    //   compute c  (waits Ar = oldest -> staging stays in flight)
    //   sched_barrier | WRITE(c+1) (waits staging, issued 1 compute-phase ago)
    const uint4* Ap = (const uint4*)wsW + w * 64 + lane;   // + K32*8*64
    const unsigned* r0base = lds + m16 * 128;
    const unsigned* r1base = lds + (16 + m16) * 128;
    const int swz = (m16 & 7);

    f32x4 acc0 = (f32x4)(0.f), acc1 = (f32x4)(0.f);
    #pragma unroll
    for (int c = 0; c < 5; ++c) {
        uint4 Ar[8];
        #pragma unroll
        for (int kk = 0; kk < 8; ++kk) Ar[kk] = Ap[(c * 8 + kk) * 512];
        __builtin_amdgcn_sched_barrier(0);     // Ar strictly older than staging
        if (c < 4) STAGE_ISSUE(c + 1);
        __builtin_amdgcn_sched_barrier(0);     // staging issued above compute
        const int boff = (c & 1) << 12;
        #pragma unroll
        for (int kk = 0; kk < 8; ++kk) {
            int off = (((kk << 2) + quad) ^ swz) << 2;
            bf16x8 A = as_bf(Ar[kk]);
            acc0 = __builtin_amdgcn_mfma_f32_16x16x32_bf16(A, ld_frag(r0base + boff + off), acc0, 0, 0, 0);
            acc1 = __builtin_amdgcn_mfma_f32_16x16x32_bf16(A, ld_frag(r1base + boff + off), acc1, 0, 0, 0);
        }
        __builtin_amdgcn_sched_barrier(0);     // WRITE stays below compute
        if (c < 4) STAGE_WRITE(c + 1);
        __syncthreads();
    }

    // prefetch GEMM2 A-frags (global, independent of LDS)
    const int m2a = w % 5, nt2a = w / 5;                   // tile w of 10
    const uint4* A2p = (const uint4*)(wsW + WS_W1F_U32) + m2a * 64 + lane;
    uint4 a20 = A2p[0], a21 = A2p[320], a22 = A2p[640], a23 = A2p[960];

    // ---- h: bias + leaky, packed o-pairs -> smHT[hwlocal*68 + o/2] ----
    #pragma unroll
    for (int nt = 0; nt < 2; ++nt) {
        f32x4 ac = nt ? acc1 : acc0;
        int r0 = nt * 16 + m16;
        #pragma unroll
        for (int rp = 0; rp < 2; ++rp) {
            int o0 = w * 16 + quad * 4 + 2 * rp;
            float v0 = ac[2 * rp]     + B1[o0];
            float v1 = ac[2 * rp + 1] + B1[o0 + 1];
            v0 = v0 > 0.f ? v0 : 0.01f * v0;
            v1 = v1 > 0.f ? v1 : 0.01f * v1;
            smHT[r0 * 68 + (o0 >> 1)] = pack2bf(v0, v1);
        }
    }
    __syncthreads();   // smHT ready

    // ---- GEMM2: tile (m2, nt2); wave w -> tile w; waves 0,1 also tiles 8,9 ----
    {
        f32x4 c2 = (f32x4)(0.f);
        const unsigned* Bb = smHT + (nt2a * 16 + m16) * 68 + quad * 4;
        c2 = __builtin_amdgcn_mfma_f32_16x16x32_bf16(as_bf(a20), ld_frag(Bb +  0), c2, 0, 0, 0);
        c2 = __builtin_amdgcn_mfma_f32_16x16x32_bf16(as_bf(a21), ld_frag(Bb + 16), c2, 0, 0, 0);
        c2 = __builtin_amdgcn_mfma_f32_16x16x32_bf16(as_bf(a22), ld_frag(Bb + 32), c2, 0, 0, 0);
        c2 = __builtin_amdgcn_mfma_f32_16x16x32_bf16(as_bf(a23), ld_frag(Bb + 48), c2, 0, 0, 0);
        int hw = hw0 + nt2a * 16 + m16;
        if (hw < HW_) {
            #pragma unroll
            for (int r = 0; r < 4; ++r) {
                int o2 = m2a * 16 + quad * 4 + r;
                if (o2 >= OUTD_) continue;
                float aa = c2[r] + B2[o2];
                unsigned dst; float val;
                if (o2 < 36) {
                    int an9 = o2 >> 2, kk = o2 & 3;
                    val = (kk < 2) ? (sigmoidf_(aa) - 0.5f) : aa;
                    dst = OFFS_OFF + b * 1764 + an9 * 196 + kk * 49 + hw;
                } else if (o2 < 45) {
                    val = sigmoidf_(aa);
                    dst = CONF_OFF + b * 441 + (o2 - 36) * 49 + hw;
                } else {
                    val = aa;
                    dst = CLS_OFF + b * 980 + (o2 - 45) * 49 + hw;
                }
                out[dst] = val;
            }
        }
    }
    if (w < 2) {       // tiles 8,9: m2 = 3+w, nt2 = 1
        const int m2b = 3 + w;
        const uint4* A3p = (const uint4*)(wsW + WS_W1F_U32) + m2b * 64 + lane;
        uint4 b20 = A3p[0], b21 = A3p[320], b22 = A3p[640], b23 = A3p[960];
        f32x4 c2 = (f32x4)(0.f);
        const unsigned* Bb = smHT + (16 + m16) * 68 + quad * 4;
        c2 = __builtin_amdgcn_mfma_f32_16x16x32_bf16(as_bf(b20), ld_frag(Bb +  0), c2, 0, 0, 0);
        c2 = __builtin_amdgcn_mfma_f32_16x16x32_bf16(as_bf(b21), ld_frag(Bb + 16), c2, 0, 0, 0);
        c2 = __builtin_amdgcn_mfma_f32_16x16x32_bf16(as_bf(b22), ld_frag(Bb + 32), c2, 0, 0, 0);
        c2 = __builtin_amdgcn_mfma_f32_16x16x32_bf16(as_bf(b23), ld_frag(Bb + 48), c2, 0, 0, 0);
        int hw = hw0 + 16 + m16;
        if (hw < HW_) {
            #pragma unroll
            for (int r = 0; r < 4; ++r) {
                int o2 = m2b * 16 + quad * 4 + r;
                if (o2 >= OUTD_) continue;
                float aa = c2[r] + B2[o2];
                unsigned dst; float val;
                if (o2 < 36) {
                    int an9 = o2 >> 2, kk = o2 & 3;
                    val = (kk < 2) ? (sigmoidf_(aa) - 0.5f) : aa;
                    dst = OFFS_OFF + b * 1764 + an9 * 196 + kk * 49 + hw;
                } else if (o2 < 45) {
                    val = sigmoidf_(aa);
                    dst = CONF_OFF + b * 441 + (o2 - 36) * 49 + hw;
                } else {
                    val = aa;
                    dst = CLS_OFF + b * 980 + (o2 - 45) * 49 + hw;
                }
                out[dst] = val;
            }
        }
    }

    // ---- IoU: wave-uniform p, g = lane (<40), unrolled, coalesced stores ----
    {
        int gl = (lane < NGT_) ? lane : 0;
        const float* gb = bbox + b * 200 + gl * 5;
        float gx1 = gb[0], gy1 = gb[1], gx2 = gb[2], gy2 = gb[3];
        float gA = (gx2 - gx1) * (gy2 - gy1);
        const int pstart = half ? 221 : 0;
        const int pend   = half ? NP_ : 221;
        #pragma unroll 4
        for (int p = pstart + w; p < pend; p += 8) {
            int a9 = p / 49, r = p - a9 * 49;
            float2 ct = *(const float2*)(grd + b * 98 + 2 * r);
            float hx = anc[2 * a9] * 0.5f,  hy = anc[2 * a9 + 1] * 0.5f;
            float px1 = ct.x - hx, py1 = ct.y - hy, px2 = ct.x + hx, py2 = ct.y + hy;
            float pA = (px2 - px1) * (py2 - py1);
            float legal = (fminf(fminf(px1, py1), fminf(px2, py2)) > 0.f) ? 1.f : 0.f;
            float tlx = fmaxf(px1, gx1), tly = fmaxf(py1, gy1);
            float brx = fminf(px2, gx2), bry = fminf(py2, gy2);
            float dx = fmaxf(brx - tlx, 0.f), dy = fmaxf(bry - tly, 0.f);
            float inter = dx * dy * legal;
            float iou = __fdividef(inter, gA + pA - inter);
            if (lane < NGT_)
                out[IOU_OFF + b * (NP_ * NGT_) + p * 40 + lane] = iou;
        }
    }
}

extern "C" void kernel_launch(void* const* d_in, const int* in_sizes, int n_in,
                              void* d_out, int out_size, void* d_ws, size_t ws_size,
                              hipStream_t stream) {
    const float* F  = (const float*)d_in[0];
    const float* G  = (const float*)d_in[1];
    const float* BB = (const float*)d_in[2];
    const float* AN = (const float*)d_in[3];
    const float* W1 = (const float*)d_in[4];
    const float* B1 = (const float*)d_in[5];
    const float* W2 = (const float*)d_in[6];
    const float* B2 = (const float*)d_in[7];
    float* out = (float*)d_out;
    unsigned* wsu = (unsigned*)d_ws;

    prep_w<<<340, 256, 0, stream>>>(W1, W2, wsu);
    fused_main<<<512, 512, 0, stream>>>(F, G, BB, AN, wsu, B1, B2, out);
}

// Round 6
// 132.448 us; speedup vs baseline: 1.0046x; 1.0046x over previous
//
#include <hip/hip_runtime.h>

// SingleStageDetector, R15 = structural rewrite of staging:
// R9-R14 post-mortem: any HBM->VGPR->LDS staging pipeline gets collapsed by
// the compiler (R13/R14 VGPR=52 vs >=66 required: prefetch never survived);
// all five schedules emitted the same serialized staging -> 42.3us, HBM 26%.
// Fix = the guide's Common-mistake #1: __builtin_amdgcn_global_load_lds
// (no dest register -> nothing to sink; vmcnt-tracked; zero VALU).
//   - 1 block per image (grid 256 = 1/CU, tail-less). F staged as a LINEAR
//     f32 copy: 5 chunks x 12544 dwords (= 256ch x 49hw exactly), 7
//     global_load_lds_dwordx4 per wave per chunk, double-buffered 2x50KB.
//   - fragments read lds[ch*49+hw]: stride 49 (odd) -> 2-way bank = free,
//     no swizzle; 4x ds_read2_b32 + 4x v_cvt_pk_bf16_f32 per bf16x8 frag.
//     Pad columns hw>=49 read finite garbage -> pollute only discarded
//     MFMA output columns (columns are independent).
//   - per-chunk A-frag burst BEFORE staging issue: Ar waits are counted
//     vmcnt (older than staging) -> staging stays in flight through the
//     whole compute phase; the only staging wait is the chunk-end
//     __syncthreads (~1 compute phase after issue ~ delivery time).
//   - 8 waves = 4 o-tiles x 2 hw-tiles, acc[2][2]; h -> smHT (64x68,
//     aliases buf0) -> GEMM2 20 tiles -> epilogue -> IoU.
// prep_w unchanged: W1/W2 -> fragment-ready bf16 images in ws.

#define CIN_  1280
#define HW_   49
#define HID_  128
#define OUTD_ 65
#define NGT_  40
#define NP_   441

// flat output offsets (elements), reference return order
#define CONF_OFF 0
#define OFFS_OFF 112896   // 256*9*49
#define CLS_OFF  564480   // + 256*9*4*49
#define IOU_OFF  815360   // + 256*20*49 ; total 5,331,200

// ws layout (u32): W1f frags ((K32*8+mt)*64+lane)*4+sub, then W2f frags
#define WS_W1F_U32 81920u
#define WS_W2F_U32 5120u

#define CHUNK_DW 12544    // 256 ch * 49 hw

typedef __bf16 bf16x8 __attribute__((ext_vector_type(8)));
typedef float  f32x4  __attribute__((ext_vector_type(4)));

__device__ __forceinline__ unsigned pack2bf(float lo, float hi) {
    unsigned short a = __builtin_bit_cast(unsigned short, (__bf16)lo);
    unsigned short b = __builtin_bit_cast(unsigned short, (__bf16)hi);
    return (unsigned)a | ((unsigned)b << 16);   // compiler: v_cvt_pk_bf16_f32
}
__device__ __forceinline__ float sigmoidf_(float v) { return 1.f / (1.f + __expf(-v)); }

__device__ __forceinline__ bf16x8 ld_frag(const unsigned* p) {
    union { uint4 u; bf16x8 v; } x;
    x.u = *(const uint4*)p;                       // 16B-aligned ds_read_b128
    return x.v;
}
__device__ __forceinline__ bf16x8 as_bf(uint4 u) {
    union { uint4 u; bf16x8 v; } x; x.u = u; return x.v;
}
// 8 f32 at stride 49 dwords -> bf16x8 (4x ds_read2_b32 + 4x cvt_pk)
__device__ __forceinline__ bf16x8 frag_from_f32(const float* p) {
    union { unsigned u[4]; bf16x8 v; } x;
    #pragma unroll
    for (int j = 0; j < 4; ++j)
        x.u[j] = pack2bf(p[(2 * j) * 49], p[(2 * j + 1) * 49]);
    return x.v;
}
// async global->LDS, 16B per lane; lds dest must be wave-uniform
__device__ __forceinline__ void gload_lds16(const float* g, unsigned* l) {
    __builtin_amdgcn_global_load_lds(
        (const __attribute__((address_space(1))) unsigned*)g,
        (__attribute__((address_space(3))) unsigned*)l, 16, 0, 0);
}

// ---------------------------------------------------------------------------
// prep_w: W1 (128,1280) + W2 (65,128) -> fragment-ready bf16 images. (R8.)
// ---------------------------------------------------------------------------
__global__ __launch_bounds__(256) void prep_w(
    const float* __restrict__ W1, const float* __restrict__ W2,
    unsigned* __restrict__ ws)
{
    int X = blockIdx.x * 256 + threadIdx.x;       // 0..87039
    if (X < (int)WS_W1F_U32) {
        int sub = X & 3, lane = (X >> 2) & 63, f = X >> 8;
        int mt = f & 7, K32 = f >> 3;
        int o = mt * 16 + (lane & 15);
        int c = K32 * 32 + (lane >> 4) * 8 + sub * 2;
        float2 v = *(const float2*)(W1 + o * CIN_ + c);
        ws[X] = pack2bf(v.x, v.y);
    } else {
        int Y = X - (int)WS_W1F_U32;              // 0..5119
        int sub = Y & 3, lane = (Y >> 2) & 63, f = Y >> 8;
        int mt2 = f % 5, ks2 = f / 5;
        int o2 = mt2 * 16 + (lane & 15);
        int c = ks2 * 32 + (lane >> 4) * 8 + sub * 2;
        unsigned val = 0;
        if (o2 < OUTD_) {
            float2 v = *(const float2*)(W2 + o2 * HID_ + c);
            val = pack2bf(v.x, v.y);
        }
        ws[WS_W1F_U32 + Y] = val;
    }
}

// ---------------------------------------------------------------------------
// fused_main: 1 block per image. LDS = 2 x 12544 dwords (f32 chunk copies,
// linear) + overrun pad. smHT (64x68 u32) aliases buffer 0 after the K-loop.
// ---------------------------------------------------------------------------
__global__ __launch_bounds__(512, 2) void fused_main(
    const float* __restrict__ F,     // (256,1280,7,7)
    const float* __restrict__ grd,   // (256,7,7,2)
    const float* __restrict__ bbox,  // (256,40,5)
    const float* __restrict__ anc,   // (9,2)
    const unsigned* __restrict__ wsW,
    const float* __restrict__ B1,    // (128,)
    const float* __restrict__ B2,    // (65,)
    float* __restrict__ out)
{
    __shared__ __align__(16) unsigned lds[2 * CHUNK_DW + 64];  // 100,864 B
    unsigned* smHT = lds;                                      // alias, post-K

    const int tid  = threadIdx.x;
    const int b    = blockIdx.x;
    const int lane = tid & 63;
    const int w    = tid >> 6;         // 0..7
    const int wo   = w >> 1;           // o-tile  (4 x 32 outputs)
    const int wh   = w & 1;            // hw-tile (2 x 32 rows)
    const int quad = lane >> 4;
    const int m16  = lane & 15;

    const float* Fb = F + b * (CIN_ * HW_);

    // linear async chunk copy: wave w covers dwords [w*1536, w*1536+1536),
    // wave 7 also the tail [12288, 12544). 16B/lane, 1KB/instr, coalesced.
    #define STAGE(c)                                                         \
        {                                                                    \
            const float* srcb = Fb + (c) * CHUNK_DW;                         \
            unsigned*    dstb = lds + (((c) & 1) ? CHUNK_DW : 0);            \
            _Pragma("unroll")                                                \
            for (int i = 0; i < 6; ++i) {                                    \
                int s0 = w * 1536 + i * 256;                                 \
                gload_lds16(srcb + s0 + lane * 4, dstb + s0);                \
            }                                                                \
            if (w == 7) gload_lds16(srcb + 12288 + lane * 4, dstb + 12288);  \
        }

    // ---- prologue: stage chunk 0 (startup delivery exposed once) ----
    STAGE(0);
    __syncthreads();

    // ---- K-loop: 5 chunks x 8 K32-steps ----
    const uint4* Af = (const uint4*)wsW;
    f32x4 acc[2][2] = {{(f32x4)(0.f), (f32x4)(0.f)}, {(f32x4)(0.f), (f32x4)(0.f)}};

    #pragma unroll
    for (int c = 0; c < 5; ++c) {
        // A-frag burst for this chunk (oldest in vmem FIFO: its waits are
        // counted and never drain the staging issued below)
        uint4 Ar[8][2];
        #pragma unroll
        for (int kk = 0; kk < 8; ++kk) {
            #pragma unroll
            for (int mo = 0; mo < 2; ++mo)
                Ar[kk][mo] = Af[(((c * 8 + kk) * 8) + (wo * 2 + mo)) * 64 + lane];
        }
        __builtin_amdgcn_sched_barrier(0);
        if (c < 4) STAGE(c + 1);
        __builtin_amdgcn_sched_barrier(0);

        const float* fb = (const float*)(lds + ((c & 1) ? CHUNK_DW : 0));
        #pragma unroll
        for (int kk = 0; kk < 8; ++kk) {
            bf16x8 A0 = as_bf(Ar[kk][0]);
            bf16x8 A1 = as_bf(Ar[kk][1]);
            #pragma unroll
            for (int nh = 0; nh < 2; ++nh) {
                const float* pb = fb + (kk * 32 + quad * 8) * 49
                                     + (wh * 32 + nh * 16 + m16);
                bf16x8 Bf = frag_from_f32(pb);
                acc[0][nh] = __builtin_amdgcn_mfma_f32_16x16x32_bf16(A0, Bf, acc[0][nh], 0, 0, 0);
                acc[1][nh] = __builtin_amdgcn_mfma_f32_16x16x32_bf16(A1, Bf, acc[1][nh], 0, 0, 0);
            }
        }
        __builtin_amdgcn_sched_barrier(0);
        __syncthreads();   // drains staging(c+1): issued one compute phase ago
    }

    // ---- h: bias + leaky, packed o-pairs -> smHT[row*68 + o/2] ----
    // row = (wh*2+nh)*16 + m16 (hw local), o = (wo*2+mo)*16 + quad*4 + r
    #pragma unroll
    for (int mo = 0; mo < 2; ++mo) {
        #pragma unroll
        for (int nh = 0; nh < 2; ++nh) {
            int row = (wh * 2 + nh) * 16 + m16;
            #pragma unroll
            for (int rp = 0; rp < 2; ++rp) {
                int o0 = (wo * 2 + mo) * 16 + quad * 4 + 2 * rp;
                float v0 = acc[mo][nh][2 * rp]     + B1[o0];
                float v1 = acc[mo][nh][2 * rp + 1] + B1[o0 + 1];
                v0 = v0 > 0.f ? v0 : 0.01f * v0;
                v1 = v1 > 0.f ? v1 : 0.01f * v1;
                smHT[row * 68 + (o0 >> 1)] = pack2bf(v0, v1);
            }
        }
    }
    __syncthreads();   // smHT ready

    // ---- GEMM2: 20 tiles (5 o2-tiles x 4 hw-tiles); wave w: T = w, w+8, w+16
    for (int T = w; T < 20; T += 8) {
        int m2 = T % 5, nt2 = T / 5;
        const uint4* A2p = (const uint4*)(wsW + WS_W1F_U32) + m2 * 64 + lane;
        uint4 a20 = A2p[0], a21 = A2p[320], a22 = A2p[640], a23 = A2p[960];
        f32x4 c2 = (f32x4)(0.f);
        const unsigned* Bb = smHT + (nt2 * 16 + m16) * 68 + quad * 4;
        c2 = __builtin_amdgcn_mfma_f32_16x16x32_bf16(as_bf(a20), ld_frag(Bb +  0), c2, 0, 0, 0);
        c2 = __builtin_amdgcn_mfma_f32_16x16x32_bf16(as_bf(a21), ld_frag(Bb + 16), c2, 0, 0, 0);
        c2 = __builtin_amdgcn_mfma_f32_16x16x32_bf16(as_bf(a22), ld_frag(Bb + 32), c2, 0, 0, 0);
        c2 = __builtin_amdgcn_mfma_f32_16x16x32_bf16(as_bf(a23), ld_frag(Bb + 48), c2, 0, 0, 0);
        int hw = nt2 * 16 + m16;
        if (hw < HW_) {
            #pragma unroll
            for (int r = 0; r < 4; ++r) {
                int o2 = m2 * 16 + quad * 4 + r;
                if (o2 >= OUTD_) continue;
                float aa = c2[r] + B2[o2];
                unsigned dst; float val;
                if (o2 < 36) {
                    int an9 = o2 >> 2, kk = o2 & 3;
                    val = (kk < 2) ? (sigmoidf_(aa) - 0.5f) : aa;
                    dst = OFFS_OFF + b * 1764 + an9 * 196 + kk * 49 + hw;
                } else if (o2 < 45) {
                    val = sigmoidf_(aa);
                    dst = CONF_OFF + b * 441 + (o2 - 36) * 49 + hw;
                } else {
                    val = aa;
                    dst = CLS_OFF + b * 980 + (o2 - 45) * 49 + hw;
                }
                out[dst] = val;
            }
        }
    }

    // ---- IoU: wave-uniform p, g = lane (<40), coalesced stores ----
    {
        int gl = (lane < NGT_) ? lane : 0;
        const float* gb = bbox + b * 200 + gl * 5;
        float gx1 = gb[0], gy1 = gb[1], gx2 = gb[2], gy2 = gb[3];
        float gA = (gx2 - gx1) * (gy2 - gy1);
        #pragma unroll 4
        for (int p = w; p < NP_; p += 8) {
            int a9 = p / 49, r = p - a9 * 49;
            float2 ct = *(const float2*)(grd + b * 98 + 2 * r);
            float hx = anc[2 * a9] * 0.5f,  hy = anc[2 * a9 + 1] * 0.5f;
            float px1 = ct.x - hx, py1 = ct.y - hy, px2 = ct.x + hx, py2 = ct.y + hy;
            float pA = (px2 - px1) * (py2 - py1);
            float legal = (fminf(fminf(px1, py1), fminf(px2, py2)) > 0.f) ? 1.f : 0.f;
            float tlx = fmaxf(px1, gx1), tly = fmaxf(py1, gy1);
            float brx = fminf(px2, gx2), bry = fminf(py2, gy2);
            float dx = fmaxf(brx - tlx, 0.f), dy = fmaxf(bry - tly, 0.f);
            float inter = dx * dy * legal;
            float iou = __fdividef(inter, gA + pA - inter);
            if (lane < NGT_)
                out[IOU_OFF + b * (NP_ * NGT_) + p * 40 + lane] = iou;
        }
    }
}

extern "C" void kernel_launch(void* const* d_in, const int* in_sizes, int n_in,
                              void* d_out, int out_size, void* d_ws, size_t ws_size,
                              hipStream_t stream) {
    const float* F  = (const float*)d_in[0];
    const float* G  = (const float*)d_in[1];
    const float* BB = (const float*)d_in[2];
    const float* AN = (const float*)d_in[3];
    const float* W1 = (const float*)d_in[4];
    const float* B1 = (const float*)d_in[5];
    const float* W2 = (const float*)d_in[6];
    const float* B2 = (const float*)d_in[7];
    float* out = (float*)d_out;
    unsigned* wsu = (unsigned*)d_ws;

    prep_w<<<340, 256, 0, stream>>>(W1, W2, wsu);
    fused_main<<<256, 512, 0, stream>>>(F, G, BB, AN, wsu, B1, B2, out);
}